// Round 1
// baseline (89883.167 us; speedup 1.0000x reference)
//
#include <hip/hip_runtime.h>
#include <math.h>

#define BB 32
#define TT 64
#define INPW 90
#define NU 4
#define NSEG 16
#define NH1 2048
#define NHC 1024
#define NHD 1024
#define NZ 512

struct CellJob {
  const float* x0; int x0ld; const float* w0; int w0ld; int K0;
  const float* x1; int x1ld; const float* w1; int w1ld; int K1;
  const float* h;  int hld;  const float* whh; int whhld;
  const float* xp; int xpld;
  const float* bih; const float* bhh;
  const float* cin; int cld;
  float* cout; int coutld;
  float* hout; int houtld;
  int H;
};
struct CellJobs2 { CellJob j[2]; };

__device__ __forceinline__ float sigf(float v) { return 1.0f / (1.0f + __expf(-v)); }

template<int JT, int MPT>
__device__ __forceinline__ void cell_accum(
    const float* __restrict__ X, int xld,
    const float* __restrict__ W, int wld, int K,
    int H, int j0, int tid, int tx, int ty,
    float (&acc)[MPT], float (*Wt)[65], float (*Xt)[65]) {
  constexpr int R = 4 * JT;
  if (!X) return;
  for (int k0 = 0; k0 < K; k0 += 64) {
    for (int e = tid; e < BB * 64; e += 256) {
      int r = e >> 6, c = e & 63;
      Xt[r][c] = (k0 + c < K) ? X[(long)r * xld + k0 + c] : 0.0f;
    }
    for (int e = tid; e < R * 64; e += 256) {
      int r = e >> 6, c = e & 63;
      int wr = (r / JT) * H + j0 + (r % JT);
      Wt[r][c] = (k0 + c < K) ? W[(long)wr * wld + k0 + c] : 0.0f;
    }
    __syncthreads();
#pragma unroll 8
    for (int kk = 0; kk < 64; ++kk) {
      float wv = Wt[tx][kk];
#pragma unroll
      for (int mm = 0; mm < MPT; ++mm)
        acc[mm] += Xt[ty * MPT + mm][kk] * wv;
    }
    __syncthreads();
  }
}

// One LSTM cell step. Block computes JT hidden units x 4 gates x all 32 batch rows.
// g = x0@w0^T + x1@w1^T + h@whh^T + (xp or bih) + bhh; then gate math, writes h,c.
template<int JT>
__global__ __launch_bounds__(256) void cell_kernel(CellJobs2 jobs) {
  constexpr int R = 4 * JT;
  constexpr int GP = 256 / R;
  constexpr int MPT = 32 / GP;
  __shared__ float Wt[R][65];
  __shared__ float Xt[BB][65];
  const CellJob J = jobs.j[blockIdx.y];
  const int tid = threadIdx.x;
  const int tx = tid % R;
  const int ty = tid / R;
  const int j0 = blockIdx.x * JT;
  const int H = J.H;
  float acc[MPT];
#pragma unroll
  for (int i = 0; i < MPT; ++i) acc[i] = 0.0f;

  cell_accum<JT, MPT>(J.x0, J.x0ld, J.w0, J.w0ld, J.K0, H, j0, tid, tx, ty, acc, Wt, Xt);
  cell_accum<JT, MPT>(J.x1, J.x1ld, J.w1, J.w1ld, J.K1, H, j0, tid, tx, ty, acc, Wt, Xt);
  cell_accum<JT, MPT>(J.h, J.hld, J.whh, J.whhld, H, H, j0, tid, tx, ty, acc, Wt, Xt);

  const int wrow = (tx / JT) * H + j0 + (tx % JT);
  float bb = J.bhh[wrow] + (J.xp ? 0.0f : J.bih[wrow]);
  float* gb = &Wt[0][0]; // reuse Wt LDS as [R][33] gate buffer (safe: loops end with sync)
#pragma unroll
  for (int mm = 0; mm < MPT; ++mm) {
    int m = ty * MPT + mm;
    float g = acc[mm] + bb;
    if (J.xp) g += J.xp[(long)m * J.xpld + wrow];
    gb[tx * 33 + m] = g;
  }
  __syncthreads();
  for (int e = tid; e < BB * JT; e += 256) {
    int j = e >> 5, m = e & 31;
    float iv = sigf(gb[(0 * JT + j) * 33 + m]);
    float fv = sigf(gb[(1 * JT + j) * 33 + m]);
    float gv = tanhf(gb[(2 * JT + j) * 33 + m]);
    float ov = sigf(gb[(3 * JT + j) * 33 + m]);
    float cold = J.cin ? J.cin[(long)m * J.cld + j0 + j] : 0.0f;
    float cnew = fv * cold + iv * gv;
    float hnew = ov * tanhf(cnew);
    J.cout[(long)m * J.coutld + j0 + j] = cnew;
    J.hout[(long)m * J.houtld + j0 + j] = hnew;
  }
}

// C[M,N] = A[M,K] @ W[N,K]^T + bias[N], optional activation. 128x128 tile, 8x8 micro.
__global__ __launch_bounds__(256) void gemm128(
    const float* __restrict__ A, int lda, const float* __restrict__ W, int ldw,
    const float* __restrict__ bias, float* __restrict__ C, int ldc,
    int M, int K, int act) {
  __shared__ float As[16][132];
  __shared__ float Bs[16][132];
  const int tid = threadIdx.x;
  const int bm = blockIdx.x, bn = blockIdx.y;
  const int tm = tid & 15, tn = tid >> 4;
  float acc[8][8] = {};
  for (int k0 = 0; k0 < K; k0 += 16) {
#pragma unroll
    for (int it = 0; it < 2; ++it) {
      int e = it * 256 + tid;
      int r = e >> 2, c4 = (e & 3) * 4;
      int m = bm * 128 + r;
      float4 v = make_float4(0.f, 0.f, 0.f, 0.f);
      if (m < M) v = *(const float4*)&A[(long)m * lda + k0 + c4];
      As[c4 + 0][r] = v.x; As[c4 + 1][r] = v.y; As[c4 + 2][r] = v.z; As[c4 + 3][r] = v.w;
      int n = bn * 128 + r;
      float4 w = *(const float4*)&W[(long)n * ldw + k0 + c4];
      Bs[c4 + 0][r] = w.x; Bs[c4 + 1][r] = w.y; Bs[c4 + 2][r] = w.z; Bs[c4 + 3][r] = w.w;
    }
    __syncthreads();
#pragma unroll
    for (int kk = 0; kk < 16; ++kk) {
      float4 a0 = *(const float4*)&As[kk][tm * 8];
      float4 a1 = *(const float4*)&As[kk][tm * 8 + 4];
      float4 b0 = *(const float4*)&Bs[kk][tn * 8];
      float4 b1 = *(const float4*)&Bs[kk][tn * 8 + 4];
      float av[8] = {a0.x, a0.y, a0.z, a0.w, a1.x, a1.y, a1.z, a1.w};
      float bv[8] = {b0.x, b0.y, b0.z, b0.w, b1.x, b1.y, b1.z, b1.w};
#pragma unroll
      for (int i = 0; i < 8; ++i)
#pragma unroll
        for (int j = 0; j < 8; ++j)
          acc[i][j] += av[i] * bv[j];
    }
    __syncthreads();
  }
#pragma unroll
  for (int i = 0; i < 8; ++i) {
    int m = bm * 128 + tm * 8 + i;
    if (m >= M) continue;
#pragma unroll
    for (int j = 0; j < 8; ++j) {
      int n = bn * 128 + tn * 8 + j;
      float v = acc[i][j] + bias[n];
      if (act == 1) v = tanhf(v);
      else if (act == 2) v = log1pf(__expf(v));
      C[(long)m * ldc + n] = v;
    }
  }
}

__global__ void concat_ht_kernel(const float* __restrict__ hf, const float* __restrict__ hb,
                                 float* __restrict__ ht) {
  int e = blockIdx.x * 256 + threadIdx.x;
  if (e >= BB * 2 * NH1) return;
  int b = e / (2 * NH1), k = e % (2 * NH1);
  ht[e] = (k < NH1) ? hf[b * NH1 + k] : hb[b * NH1 + k - NH1];
}

__global__ void zcalc_kernel(const float* __restrict__ zm, const float* __restrict__ zs,
                             const float* __restrict__ eps, float* __restrict__ z) {
  int e = blockIdx.x * 256 + threadIdx.x;
  if (e < BB * NZ) z[e] = zm[e] + eps[e] * zs[e];
}

__global__ void zero_kernel(float* p, int n) {
  int e = blockIdx.x * 256 + threadIdx.x;
  if (e < n) p[e] = 0.0f;
}

// p = h @ w4^T + b4 ; write raw p to pbuf (next-step input) and to output slot.
__global__ void proj_kernel(const float* __restrict__ h, const float* __restrict__ w4,
                            const float* __restrict__ b4, float* __restrict__ pbuf,
                            float* __restrict__ outp) {
  int n = blockIdx.x, lane = threadIdx.x;
  float wr[16];
#pragma unroll
  for (int i = 0; i < 16; ++i) wr[i] = w4[n * NHD + lane + 64 * i];
  for (int b = 0; b < BB; ++b) {
    float s = 0.0f;
#pragma unroll
    for (int i = 0; i < 16; ++i) s += wr[i] * h[b * NHD + lane + 64 * i];
#pragma unroll
    for (int off = 32; off > 0; off >>= 1) s += __shfl_down(s, off);
    if (lane == 0) {
      float v = s + b4[n];
      pbuf[b * INPW + n] = v;
      outp[(long)b * (TT * INPW) + n] = v;
    }
  }
}

__global__ void softmax_kernel(float* __restrict__ out) {
  long row = blockIdx.x;
  float* p = out + row * INPW;
  int lane = threadIdx.x;
  float v0 = (lane < INPW) ? p[lane] : -1e30f;
  float v1 = (lane + 64 < INPW) ? p[lane + 64] : -1e30f;
  float m = fmaxf(v0, v1);
#pragma unroll
  for (int off = 32; off > 0; off >>= 1) m = fmaxf(m, __shfl_xor(m, off));
  float e0 = (lane < INPW) ? __expf(v0 - m) : 0.0f;
  float e1 = (lane + 64 < INPW) ? __expf(v1 - m) : 0.0f;
  float sum = e0 + e1;
#pragma unroll
  for (int off = 32; off > 0; off >>= 1) sum += __shfl_xor(sum, off);
  float inv = 1.0f / sum;
  if (lane < INPW) p[lane] = e0 * inv;
  if (lane + 64 < INPW) p[lane + 64] = e1 * inv;
}

extern "C" void kernel_launch(void* const* d_in, const int* in_sizes, int n_in,
                              void* d_out, int out_size, void* d_ws, size_t ws_size,
                              hipStream_t stream) {
  (void)in_sizes; (void)n_in; (void)out_size;
  const float* x        = (const float*)d_in[0];
  const float* eps      = (const float*)d_in[1];
  const float* e0f_wih  = (const float*)d_in[2];
  const float* e0f_whh  = (const float*)d_in[3];
  const float* e0f_bih  = (const float*)d_in[4];
  const float* e0f_bhh  = (const float*)d_in[5];
  const float* e0b_wih  = (const float*)d_in[6];
  const float* e0b_whh  = (const float*)d_in[7];
  const float* e0b_bih  = (const float*)d_in[8];
  const float* e0b_bhh  = (const float*)d_in[9];
  const float* e1f_wih  = (const float*)d_in[10];
  const float* e1f_whh  = (const float*)d_in[11];
  const float* e1f_bih  = (const float*)d_in[12];
  const float* e1f_bhh  = (const float*)d_in[13];
  const float* e1b_wih  = (const float*)d_in[14];
  const float* e1b_whh  = (const float*)d_in[15];
  const float* e1b_bih  = (const float*)d_in[16];
  const float* e1b_bhh  = (const float*)d_in[17];
  const float* wm  = (const float*)d_in[18];
  const float* bm  = (const float*)d_in[19];
  const float* wsw = (const float*)d_in[20];
  const float* bsv = (const float*)d_in[21];
  const float* w2  = (const float*)d_in[22];
  const float* b2  = (const float*)d_in[23];
  const float* c0_wih = (const float*)d_in[24];
  const float* c0_whh = (const float*)d_in[25];
  const float* c0_bih = (const float*)d_in[26];
  const float* c0_bhh = (const float*)d_in[27];
  const float* c1_wih = (const float*)d_in[28];
  const float* c1_whh = (const float*)d_in[29];
  const float* c1_bih = (const float*)d_in[30];
  const float* c1_bhh = (const float*)d_in[31];
  const float* w3 = (const float*)d_in[32];
  const float* b3 = (const float*)d_in[33];
  const float* d1_wih = (const float*)d_in[34];
  const float* d1_whh = (const float*)d_in[35];
  const float* d1_bih = (const float*)d_in[36];
  const float* d1_bhh = (const float*)d_in[37];
  const float* d2_wih = (const float*)d_in[38];
  const float* d2_whh = (const float*)d_in[39];
  const float* d2_bih = (const float*)d_in[40];
  const float* d2_bhh = (const float*)d_in[41];
  const float* w4 = (const float*)d_in[42];
  const float* b4 = (const float*)d_in[43];

  float* out = (float*)d_out;
  float* zm_out = out + (size_t)BB * TT * INPW;
  float* zs_out = zm_out + BB * NZ;

  float* wsp = (float*)d_ws;
  size_t off = 0;
  auto alloc = [&](size_t n) { float* p = wsp + off; off += (n + 63) & ~(size_t)63; return p; };
  float* y0  = alloc((size_t)BB * TT * 2 * NH1);
  float* c0f = alloc(BB * NH1); float* c0b = alloc(BB * NH1);
  float* c1f = alloc(BB * NH1); float* c1b = alloc(BB * NH1);
  float* hpf = alloc(2 * BB * NH1); float* hpb = alloc(2 * BB * NH1);
  float* htb = alloc(BB * 2 * NH1);
  float* zbuf = alloc(BB * NZ);
  float* tvec = alloc(BB * 4 * NHC);
  float* yc0 = alloc(BB * NU * NHC);
  float* emb = alloc(BB * NU * NHC);
  float* cc0 = alloc(BB * NHC); float* cc1 = alloc(BB * NHC);
  float* sall = alloc((size_t)BB * NU * 4 * NHD);
  float* dh1 = alloc(2 * BB * NHD); float* dh2 = alloc(2 * BB * NHD);
  float* dc1 = alloc(BB * NHD); float* dc2 = alloc(BB * NHD);
  float* pbuf = alloc(BB * INPW);
  size_t need_xp = off + 2 * ((size_t)BB * TT * 4 * NH1 + 64);
  bool use_xp = ws_size >= need_xp * sizeof(float);
  float* xp1f = nullptr; float* xp1b = nullptr;
  if (use_xp) { xp1f = alloc((size_t)BB * TT * 4 * NH1); xp1b = alloc((size_t)BB * TT * 4 * NH1); }

  // ---------- encoder layer 0 (bi-dir, fused into one launch per step) ----------
  for (int s = 0; s < TT; ++s) {
    CellJobs2 js{};
    int tf = s, tb = TT - 1 - s;
    CellJob& F = js.j[0];
    F.x0 = x + tf * INPW; F.x0ld = TT * INPW; F.w0 = e0f_wih; F.w0ld = INPW; F.K0 = INPW;
    F.h = s ? y0 + (size_t)(tf - 1) * 2 * NH1 : nullptr; F.hld = TT * 2 * NH1;
    F.whh = e0f_whh; F.whhld = NH1;
    F.bih = e0f_bih; F.bhh = e0f_bhh;
    F.cin = s ? c0f : nullptr; F.cld = NH1;
    F.cout = c0f; F.coutld = NH1;
    F.hout = y0 + (size_t)tf * 2 * NH1; F.houtld = TT * 2 * NH1;
    F.H = NH1;
    CellJob& Bj = js.j[1];
    Bj = F;
    Bj.x0 = x + tb * INPW; Bj.w0 = e0b_wih;
    Bj.h = s ? y0 + (size_t)(tb + 1) * 2 * NH1 + NH1 : nullptr;
    Bj.whh = e0b_whh; Bj.bih = e0b_bih; Bj.bhh = e0b_bhh;
    Bj.cin = s ? c0b : nullptr; Bj.cout = c0b;
    Bj.hout = y0 + (size_t)tb * 2 * NH1 + NH1;
    cell_kernel<16><<<dim3(NH1 / 16, 2), 256, 0, stream>>>(js);
  }

  // ---------- layer-1 input projections (big GEMMs) ----------
  if (use_xp) {
    gemm128<<<dim3(16, 64), 256, 0, stream>>>(y0, 2 * NH1, e1f_wih, 2 * NH1, e1f_bih,
                                              xp1f, 4 * NH1, BB * TT, 2 * NH1, 0);
    gemm128<<<dim3(16, 64), 256, 0, stream>>>(y0, 2 * NH1, e1b_wih, 2 * NH1, e1b_bih,
                                              xp1b, 4 * NH1, BB * TT, 2 * NH1, 0);
  }

  // ---------- encoder layer 1 ----------
  for (int s = 0; s < TT; ++s) {
    CellJobs2 js{};
    int tf = s, tb = TT - 1 - s;
    CellJob& F = js.j[0];
    if (use_xp) { F.xp = xp1f + (size_t)tf * 4 * NH1; F.xpld = TT * 4 * NH1; }
    else { F.x0 = y0 + (size_t)tf * 2 * NH1; F.x0ld = TT * 2 * NH1; F.w0 = e1f_wih; F.w0ld = 2 * NH1; F.K0 = 2 * NH1; }
    F.h = s ? hpf + (size_t)((s - 1) & 1) * BB * NH1 : nullptr; F.hld = NH1;
    F.whh = e1f_whh; F.whhld = NH1;
    F.bih = e1f_bih; F.bhh = e1f_bhh;
    F.cin = s ? c1f : nullptr; F.cld = NH1;
    F.cout = c1f; F.coutld = NH1;
    F.hout = hpf + (size_t)(s & 1) * BB * NH1; F.houtld = NH1;
    F.H = NH1;
    CellJob& Bj = js.j[1];
    Bj = F;
    if (use_xp) { Bj.xp = xp1b + (size_t)tb * 4 * NH1; }
    else { Bj.x0 = y0 + (size_t)tb * 2 * NH1; Bj.w0 = e1b_wih; }
    Bj.h = s ? hpb + (size_t)((s - 1) & 1) * BB * NH1 : nullptr;
    Bj.whh = e1b_whh; Bj.bih = e1b_bih; Bj.bhh = e1b_bhh;
    Bj.cin = s ? c1b : nullptr; Bj.cout = c1b;
    Bj.hout = hpb + (size_t)(s & 1) * BB * NH1;
    cell_kernel<16><<<dim3(NH1 / 16, 2), 256, 0, stream>>>(js);
  }

  // ---------- latent ----------
  concat_ht_kernel<<<dim3((BB * 2 * NH1 + 255) / 256), 256, 0, stream>>>(
      hpf + BB * NH1, hpb + BB * NH1, htb);
  gemm128<<<dim3(1, NZ / 128), 256, 0, stream>>>(htb, 2 * NH1, wm, 2 * NH1, bm,
                                                 zm_out, NZ, BB, 2 * NH1, 0);
  gemm128<<<dim3(1, NZ / 128), 256, 0, stream>>>(htb, 2 * NH1, wsw, 2 * NH1, bsv,
                                                 zs_out, NZ, BB, 2 * NH1, 2);
  zcalc_kernel<<<dim3((BB * NZ + 255) / 256), 256, 0, stream>>>(zm_out, zs_out, eps, zbuf);
  gemm128<<<dim3(1, 4 * NHC / 128), 256, 0, stream>>>(zbuf, NZ, w2, NZ, b2,
                                                      tvec, 4 * NHC, BB, NZ, 1);

  // ---------- conductor (2-layer LSTM, 4 steps, zero input) ----------
  for (int u = 0; u < NU; ++u) {
    {
      CellJobs2 js{};
      CellJob& J = js.j[0];
      J.h = u ? yc0 + (size_t)(u - 1) * NHC : tvec; J.hld = u ? NU * NHC : 4 * NHC;
      J.whh = c0_whh; J.whhld = NHC;
      J.bih = c0_bih; J.bhh = c0_bhh;
      J.cin = u ? cc0 : tvec + 2 * NHC; J.cld = u ? NHC : 4 * NHC;
      J.cout = cc0; J.coutld = NHC;
      J.hout = yc0 + (size_t)u * NHC; J.houtld = NU * NHC;
      J.H = NHC;
      js.j[1] = J;
      cell_kernel<8><<<dim3(NHC / 8, 1), 256, 0, stream>>>(js);
    }
    {
      CellJobs2 js{};
      CellJob& J = js.j[0];
      J.x0 = yc0 + (size_t)u * NHC; J.x0ld = NU * NHC; J.w0 = c1_wih; J.w0ld = NHC; J.K0 = NHC;
      J.h = u ? emb + (size_t)(u - 1) * NHC : tvec + NHC; J.hld = u ? NU * NHC : 4 * NHC;
      J.whh = c1_whh; J.whhld = NHC;
      J.bih = c1_bih; J.bhh = c1_bhh;
      J.cin = u ? cc1 : tvec + 3 * NHC; J.cld = u ? NHC : 4 * NHC;
      J.cout = cc1; J.coutld = NHC;
      J.hout = emb + (size_t)u * NHC; J.houtld = NU * NHC;
      J.H = NHC;
      js.j[1] = J;
      cell_kernel<8><<<dim3(NHC / 8, 1), 256, 0, stream>>>(js);
    }
  }

  // ---------- decoder segment-init projections, all 4 segments at once ----------
  gemm128<<<dim3(1, 4 * NHD / 128), 256, 0, stream>>>(emb, NHC, w3, NHC, b3,
                                                      sall, 4 * NHD, BB * NU, NHC, 1);
  zero_kernel<<<dim3((BB * INPW + 255) / 256), 256, 0, stream>>>(pbuf, BB * INPW);

  // ---------- hierarchical decoder ----------
  for (int t = 0; t < TT; ++t) {
    int u = t >> 4, sg = t & 15;
    {
      CellJobs2 js{};
      CellJob& J = js.j[0];
      J.x0 = emb + (size_t)u * NHC; J.x0ld = NU * NHC; J.w0 = d1_wih; J.w0ld = NHC + INPW; J.K0 = NHC;
      J.x1 = pbuf; J.x1ld = INPW; J.w1 = d1_wih + NHC; J.w1ld = NHC + INPW; J.K1 = INPW;
      J.h = sg ? dh1 + (size_t)((sg - 1) & 1) * BB * NHD : sall + (size_t)u * 4 * NHD;
      J.hld = sg ? NHD : NU * 4 * NHD;
      J.whh = d1_whh; J.whhld = NHD;
      J.bih = d1_bih; J.bhh = d1_bhh;
      J.cin = sg ? dc1 : sall + (size_t)u * 4 * NHD + 2 * NHD; J.cld = sg ? NHD : NU * 4 * NHD;
      J.cout = dc1; J.coutld = NHD;
      J.hout = dh1 + (size_t)(sg & 1) * BB * NHD; J.houtld = NHD;
      J.H = NHD;
      js.j[1] = J;
      cell_kernel<8><<<dim3(NHD / 8, 1), 256, 0, stream>>>(js);
    }
    {
      CellJobs2 js{};
      CellJob& J = js.j[0];
      J.x0 = dh1 + (size_t)(sg & 1) * BB * NHD; J.x0ld = NHD; J.w0 = d2_wih; J.w0ld = NHD; J.K0 = NHD;
      J.h = sg ? dh2 + (size_t)((sg - 1) & 1) * BB * NHD : sall + (size_t)u * 4 * NHD + NHD;
      J.hld = sg ? NHD : NU * 4 * NHD;
      J.whh = d2_whh; J.whhld = NHD;
      J.bih = d2_bih; J.bhh = d2_bhh;
      J.cin = sg ? dc2 : sall + (size_t)u * 4 * NHD + 3 * NHD; J.cld = sg ? NHD : NU * 4 * NHD;
      J.cout = dc2; J.coutld = NHD;
      J.hout = dh2 + (size_t)(sg & 1) * BB * NHD; J.houtld = NHD;
      J.H = NHD;
      js.j[1] = J;
      cell_kernel<8><<<dim3(NHD / 8, 1), 256, 0, stream>>>(js);
    }
    proj_kernel<<<dim3(INPW), 64, 0, stream>>>(
        dh2 + (size_t)(sg & 1) * BB * NHD, w4, b4, pbuf, out + (size_t)t * INPW);
  }

  // ---------- final softmax over IN ----------
  softmax_kernel<<<dim3(BB * TT), 64, 0, stream>>>(out);
}

// Round 2
// 9244.427 us; speedup vs baseline: 9.7230x; 9.7230x over previous
//
#include <hip/hip_runtime.h>
#include <math.h>

#define BB 32
#define TT 64
#define INPW 90
#define NU 4
#define NSEG 16
#define NH1 2048
#define NHC 1024
#define NHD 1024
#define NZ 512

typedef unsigned short u16;
typedef __attribute__((ext_vector_type(8))) short short8;
typedef __attribute__((ext_vector_type(4))) float f32x4;

__device__ __forceinline__ float sigf(float v) { return 1.0f / (1.0f + __expf(-v)); }

__device__ __forceinline__ u16 f2bf(float f) {
  unsigned u = __float_as_uint(f);
  unsigned r = (u + 0x7FFFu + ((u >> 16) & 1u)) >> 16;
  return (u16)r;
}
__device__ __forceinline__ float bf2f(u16 b) { return __uint_as_float(((unsigned)b) << 16); }

// ---------------- conversion kernels ----------------
__global__ void cvt_flat(const float* __restrict__ s, u16* __restrict__ d, long n) {
  long i = ((long)blockIdx.x * 256 + threadIdx.x) * 4;
  if (i >= n) return;
  float4 v = *(const float4*)&s[i];
  d[i] = f2bf(v.x); d[i + 1] = f2bf(v.y); d[i + 2] = f2bf(v.z); d[i + 3] = f2bf(v.w);
}

__global__ void cvt_pad(const float* __restrict__ s, int sld, int cols,
                        u16* __restrict__ d, int dld, int rows) {
  int c = blockIdx.x * blockDim.x + threadIdx.x;
  int r = blockIdx.y;
  if (c >= dld) return;
  d[(long)r * dld + c] = (c < cols) ? f2bf(s[(long)r * sld + c]) : (u16)0;
}

// x[b][t][90] -> xb[(t*32+b)][128] bf16 (zero-padded)
__global__ void xcvt(const float* __restrict__ x, u16* __restrict__ xb) {
  int r = blockIdx.x;          // 0..2047
  int c = threadIdx.x;         // 0..127
  int b = r & 31, t = r >> 5;
  float v = (c < INPW) ? x[((long)b * TT + t) * INPW + c] : 0.0f;
  xb[(long)r * 128 + c] = f2bf(v);
}

__global__ void zero_us(u16* p, int n) {
  int i = blockIdx.x * 256 + threadIdx.x;
  if (i < n) p[i] = 0;
}

// ---------------- MFMA LSTM cell ----------------
// G[4H x 32] = sum_seg X_seg[32][K]*W_seg[4H][K]^T (+ xp + biases) -> gates -> h,c
// Row packing: MFMA A-tile row tr (within wave w, block j0) = gate (tr&3),
// hidden j0 + 4w + (tr>>2). Lane ends with all 4 gates of one (hidden,batch).
struct BJob {
  const u16* xa; int xald; const u16* wa; int wald; int Ka;
  const u16* xb; int xbld; const u16* wb; int wbld; int Kb;
  const u16* xh; int xhld; const u16* wh; int whld; int Kh;
  const u16* xp; long xpld;
  const float* bih; const float* bhh; int add_bih;
  const float* cin; int cld;
  float* cout; int coutld;
  u16* houtb; int hbld;
  float* houtf; int hfld;
  int H;
};
struct BJobs2 { BJob j[2]; };

__global__ __launch_bounds__(256) void bcell(BJobs2 jobs) {
  __shared__ u16 As[64 * 64];
  __shared__ u16 Xs[32 * 64];
  const BJob J = jobs.j[blockIdx.y];
  const int tid = threadIdx.x;
  const int w = tid >> 6;
  const int q = (tid >> 4) & 3;
  const int ln = tid & 15;
  const int H = J.H;
  const int j0 = blockIdx.x * 16;
  f32x4 acc0 = {0.f, 0.f, 0.f, 0.f};
  f32x4 acc1 = {0.f, 0.f, 0.f, 0.f};

  // staging roles
  const int wrow0 = tid >> 3, wsl = tid & 7;
  const int wrow1 = wrow0 + 32;
  const long wr0 = (long)((wrow0 & 3) * H + j0 + ((wrow0 >> 4) << 2) + ((wrow0 >> 2) & 3));
  const long wr1 = (long)((wrow1 & 3) * H + j0 + ((wrow1 >> 4) << 2) + ((wrow1 >> 2) & 3));
  const int aoff0 = wrow0 * 64 + ((wsl ^ (wrow0 & 7)) << 3);
  const int aoff1 = wrow1 * 64 + ((wsl ^ (wrow1 & 7)) << 3);
  const int xrow = tid >> 3;
  const int xoff = xrow * 64 + ((wsl ^ (xrow & 7)) << 3);

  // fragment read offsets
  const int ar = (w << 4) + ln;
  const int a0o = ar * 64 + (((q + 0) ^ (ar & 7)) << 3);
  const int a1o = ar * 64 + (((q + 4) ^ (ar & 7)) << 3);
  const int xr0 = ln, xr1 = ln + 16;
  const int b00o = xr0 * 64 + (((q + 0) ^ (xr0 & 7)) << 3);
  const int b01o = xr0 * 64 + (((q + 4) ^ (xr0 & 7)) << 3);
  const int b10o = xr1 * 64 + (((q + 0) ^ (xr1 & 7)) << 3);
  const int b11o = xr1 * 64 + (((q + 4) ^ (xr1 & 7)) << 3);

  auto run_seg = [&](const u16* X, int xld, const u16* W, int wld, int K) {
    if (!X) return;
    uint4 v0 = *(const uint4*)&W[wr0 * wld + wsl * 8];
    uint4 v1 = *(const uint4*)&W[wr1 * wld + wsl * 8];
    uint4 xv = *(const uint4*)&X[(long)xrow * xld + wsl * 8];
    for (int k0 = 0; k0 < K; k0 += 64) {
      __syncthreads();
      *(uint4*)&As[aoff0] = v0;
      *(uint4*)&As[aoff1] = v1;
      *(uint4*)&Xs[xoff] = xv;
      __syncthreads();
      if (k0 + 64 < K) {
        v0 = *(const uint4*)&W[wr0 * wld + k0 + 64 + wsl * 8];
        v1 = *(const uint4*)&W[wr1 * wld + k0 + 64 + wsl * 8];
        xv = *(const uint4*)&X[(long)xrow * xld + k0 + 64 + wsl * 8];
      }
      short8 a0 = *(short8*)&As[a0o];
      short8 a1 = *(short8*)&As[a1o];
      short8 b00 = *(short8*)&Xs[b00o];
      short8 b01 = *(short8*)&Xs[b01o];
      short8 b10 = *(short8*)&Xs[b10o];
      short8 b11 = *(short8*)&Xs[b11o];
      acc0 = __builtin_amdgcn_mfma_f32_16x16x32_bf16(a0, b00, acc0, 0, 0, 0);
      acc0 = __builtin_amdgcn_mfma_f32_16x16x32_bf16(a1, b01, acc0, 0, 0, 0);
      acc1 = __builtin_amdgcn_mfma_f32_16x16x32_bf16(a0, b10, acc1, 0, 0, 0);
      acc1 = __builtin_amdgcn_mfma_f32_16x16x32_bf16(a1, b11, acc1, 0, 0, 0);
    }
  };
  run_seg(J.xa, J.xald, J.wa, J.wald, J.Ka);
  run_seg(J.xb, J.xbld, J.wb, J.wbld, J.Kb);
  run_seg(J.xh, J.xhld, J.wh, J.whld, J.Kh);

  const int j = j0 + (w << 2) + q;
  float b0 = J.bhh[0 * H + j], b1 = J.bhh[1 * H + j];
  float b2 = J.bhh[2 * H + j], b3 = J.bhh[3 * H + j];
  if (J.add_bih) {
    b0 += J.bih[0 * H + j]; b1 += J.bih[1 * H + j];
    b2 += J.bih[2 * H + j]; b3 += J.bih[3 * H + j];
  }
#pragma unroll
  for (int mt = 0; mt < 2; ++mt) {
    f32x4 a = mt ? acc1 : acc0;
    int m = ln + (mt << 4);
    float g0 = a[0] + b0, g1 = a[1] + b1, g2 = a[2] + b2, g3 = a[3] + b3;
    if (J.xp) {
      const u16* xr = J.xp + (long)m * J.xpld;
      g0 += bf2f(xr[0 * H + j]); g1 += bf2f(xr[1 * H + j]);
      g2 += bf2f(xr[2 * H + j]); g3 += bf2f(xr[3 * H + j]);
    }
    float iv = sigf(g0), fv = sigf(g1), gv = tanhf(g2), ov = sigf(g3);
    float co = J.cin ? J.cin[(long)m * J.cld + j] : 0.0f;
    float c = fv * co + iv * gv;
    float h = ov * tanhf(c);
    J.cout[(long)m * J.coutld + j] = c;
    J.houtb[(long)m * J.hbld + j] = f2bf(h);
    if (J.houtf) J.houtf[(long)m * J.hfld + j] = h;
  }
}

// ---------------- bf16 MFMA GEMM: C[M][N] = A[M][K] * Bw[N][K]^T + bias ----------------
// grid (M/128, N/128), 256 threads, wave = 64x64 tile, bf16 output.
__global__ __launch_bounds__(256) void gemm_bf(
    const u16* __restrict__ A, int lda, const u16* __restrict__ Bw, int ldb,
    const float* __restrict__ bias, u16* __restrict__ C, int ldc, int K) {
  __shared__ u16 Asm[128 * 64];
  __shared__ u16 Bsm[128 * 64];
  const int tid = threadIdx.x;
  const int w = tid >> 6, q = (tid >> 4) & 3, ln = tid & 15;
  const int wm = w & 1, wn = w >> 1;
  const long am0 = (long)blockIdx.x * 128;
  const long bn0 = (long)blockIdx.y * 128;
  f32x4 acc[4][4] = {};
  const int srow = tid >> 3, ssl = tid & 7;
  const u16* Ap = A + (am0 + srow) * lda + ssl * 8;
  const u16* Bp = Bw + (bn0 + srow) * ldb + ssl * 8;
  uint4 va[4], vb[4];
  int soff[4];
#pragma unroll
  for (int i = 0; i < 4; ++i) {
    va[i] = *(const uint4*)(Ap + (long)i * 32 * lda);
    vb[i] = *(const uint4*)(Bp + (long)i * 32 * ldb);
    int r = srow + i * 32;
    soff[i] = r * 64 + ((ssl ^ (r & 7)) << 3);
  }
  int k0 = 0;
  for (;;) {
    __syncthreads();
#pragma unroll
    for (int i = 0; i < 4; ++i) {
      *(uint4*)&Asm[soff[i]] = va[i];
      *(uint4*)&Bsm[soff[i]] = vb[i];
    }
    __syncthreads();
    k0 += 64;
    if (k0 < K) {
#pragma unroll
      for (int i = 0; i < 4; ++i) {
        va[i] = *(const uint4*)(Ap + k0 + (long)i * 32 * lda);
        vb[i] = *(const uint4*)(Bp + k0 + (long)i * 32 * ldb);
      }
    }
#pragma unroll
    for (int kh = 0; kh < 2; ++kh) {
      short8 af[4], bg[4];
#pragma unroll
      for (int t = 0; t < 4; ++t) {
        int arr = wm * 64 + t * 16 + ln;
        af[t] = *(short8*)&Asm[arr * 64 + (((q + 4 * kh) ^ (arr & 7)) << 3)];
        int brr = wn * 64 + t * 16 + ln;
        bg[t] = *(short8*)&Bsm[brr * 64 + (((q + 4 * kh) ^ (brr & 7)) << 3)];
      }
#pragma unroll
      for (int mt = 0; mt < 4; ++mt)
#pragma unroll
        for (int nt = 0; nt < 4; ++nt)
          acc[mt][nt] = __builtin_amdgcn_mfma_f32_16x16x32_bf16(af[mt], bg[nt], acc[mt][nt], 0, 0, 0);
    }
    if (k0 >= K) break;
  }
#pragma unroll
  for (int nt = 0; nt < 4; ++nt) {
    long n = bn0 + wn * 64 + nt * 16 + ln;
    float bv = bias ? bias[n] : 0.0f;
#pragma unroll
    for (int mt = 0; mt < 4; ++mt) {
#pragma unroll
      for (int r = 0; r < 4; ++r) {
        long m = am0 + wm * 64 + mt * 16 + (q << 2) + r;
        C[m * ldc + n] = f2bf(acc[mt][nt][r] + bv);
      }
    }
  }
}

// p = h(bf16) @ w4b^T + b4 ; pbuf bf16 [32][128], out fp32
__global__ void projb(const u16* __restrict__ h, const u16* __restrict__ w4b,
                      const float* __restrict__ b4, u16* __restrict__ pb,
                      float* __restrict__ outp) {
  int n = blockIdx.x, lane = threadIdx.x;
  float wr[16];
#pragma unroll
  for (int i = 0; i < 16; ++i) wr[i] = bf2f(w4b[n * NHD + lane + 64 * i]);
  for (int b = 0; b < BB; ++b) {
    float s = 0.0f;
#pragma unroll
    for (int i = 0; i < 16; ++i) s += wr[i] * bf2f(h[b * NHD + lane + 64 * i]);
#pragma unroll
    for (int off = 32; off > 0; off >>= 1) s += __shfl_down(s, off);
    if (lane == 0) {
      float v = s + b4[n];
      pb[b * 128 + n] = f2bf(v);
      outp[(long)b * (TT * INPW) + n] = v;
    }
  }
}

// ---------------- fp32 helper kernels (latent path + old fallback) ----------------
__global__ __launch_bounds__(256) void gemm128(
    const float* __restrict__ A, int lda, const float* __restrict__ W, int ldw,
    const float* __restrict__ bias, float* __restrict__ C, int ldc,
    int M, int K, int act, u16* __restrict__ Cb) {
  __shared__ float As[16][132];
  __shared__ float Bs[16][132];
  const int tid = threadIdx.x;
  const int bm = blockIdx.x, bn = blockIdx.y;
  const int tm = tid & 15, tn = tid >> 4;
  float acc[8][8] = {};
  for (int k0 = 0; k0 < K; k0 += 16) {
#pragma unroll
    for (int it = 0; it < 2; ++it) {
      int e = it * 256 + tid;
      int r = e >> 2, c4 = (e & 3) * 4;
      int m = bm * 128 + r;
      float4 v = make_float4(0.f, 0.f, 0.f, 0.f);
      if (m < M) v = *(const float4*)&A[(long)m * lda + k0 + c4];
      As[c4 + 0][r] = v.x; As[c4 + 1][r] = v.y; As[c4 + 2][r] = v.z; As[c4 + 3][r] = v.w;
      int n = bn * 128 + r;
      float4 w = *(const float4*)&W[(long)n * ldw + k0 + c4];
      Bs[c4 + 0][r] = w.x; Bs[c4 + 1][r] = w.y; Bs[c4 + 2][r] = w.z; Bs[c4 + 3][r] = w.w;
    }
    __syncthreads();
#pragma unroll
    for (int kk = 0; kk < 16; ++kk) {
      float4 a0 = *(const float4*)&As[kk][tm * 8];
      float4 a1 = *(const float4*)&As[kk][tm * 8 + 4];
      float4 b0 = *(const float4*)&Bs[kk][tn * 8];
      float4 b1 = *(const float4*)&Bs[kk][tn * 8 + 4];
      float av[8] = {a0.x, a0.y, a0.z, a0.w, a1.x, a1.y, a1.z, a1.w};
      float bv[8] = {b0.x, b0.y, b0.z, b0.w, b1.x, b1.y, b1.z, b1.w};
#pragma unroll
      for (int i = 0; i < 8; ++i)
#pragma unroll
        for (int j = 0; j < 8; ++j)
          acc[i][j] += av[i] * bv[j];
    }
    __syncthreads();
  }
#pragma unroll
  for (int i = 0; i < 8; ++i) {
    int m = bm * 128 + tm * 8 + i;
    if (m >= M) continue;
#pragma unroll
    for (int j = 0; j < 8; ++j) {
      int n = bn * 128 + tn * 8 + j;
      float v = acc[i][j] + bias[n];
      if (act == 1) v = tanhf(v);
      else if (act == 2) v = log1pf(__expf(v));
      C[(long)m * ldc + n] = v;
      if (Cb) Cb[(long)m * ldc + n] = f2bf(v);
    }
  }
}

__global__ void zcalc_kernel(const float* __restrict__ zm, const float* __restrict__ zs,
                             const float* __restrict__ eps, float* __restrict__ z) {
  int e = blockIdx.x * 256 + threadIdx.x;
  if (e < BB * NZ) z[e] = zm[e] + eps[e] * zs[e];
}

__global__ void zero_kernel(float* p, int n) {
  int e = blockIdx.x * 256 + threadIdx.x;
  if (e < n) p[e] = 0.0f;
}

__global__ void concat_ht_kernel(const float* __restrict__ hf, const float* __restrict__ hb,
                                 float* __restrict__ ht) {
  int e = blockIdx.x * 256 + threadIdx.x;
  if (e >= BB * 2 * NH1) return;
  int b = e / (2 * NH1), k = e % (2 * NH1);
  ht[e] = (k < NH1) ? hf[b * NH1 + k] : hb[b * NH1 + k - NH1];
}

__global__ void softmax_kernel(float* __restrict__ out) {
  long row = blockIdx.x;
  float* p = out + row * INPW;
  int lane = threadIdx.x;
  float v0 = (lane < INPW) ? p[lane] : -1e30f;
  float v1 = (lane + 64 < INPW) ? p[lane + 64] : -1e30f;
  float m = fmaxf(v0, v1);
#pragma unroll
  for (int off = 32; off > 0; off >>= 1) m = fmaxf(m, __shfl_xor(m, off));
  float e0 = (lane < INPW) ? __expf(v0 - m) : 0.0f;
  float e1 = (lane + 64 < INPW) ? __expf(v1 - m) : 0.0f;
  float sum = e0 + e1;
#pragma unroll
  for (int off = 32; off > 0; off >>= 1) sum += __shfl_xor(sum, off);
  float inv = 1.0f / sum;
  if (lane < INPW) p[lane] = e0 * inv;
  if (lane + 64 < INPW) p[lane + 64] = e1 * inv;
}

// ---------------- old fp32 cell (fallback path) ----------------
struct CellJob {
  const float* x0; int x0ld; const float* w0; int w0ld; int K0;
  const float* x1; int x1ld; const float* w1; int w1ld; int K1;
  const float* h;  int hld;  const float* whh; int whhld;
  const float* xp; int xpld;
  const float* bih; const float* bhh;
  const float* cin; int cld;
  float* cout; int coutld;
  float* hout; int houtld;
  int H;
};
struct CellJobs2 { CellJob j[2]; };

template<int JT, int MPT>
__device__ __forceinline__ void cell_accum(
    const float* __restrict__ X, int xld,
    const float* __restrict__ W, int wld, int K,
    int H, int j0, int tid, int tx, int ty,
    float (&acc)[MPT], float (*Wt)[65], float (*Xt)[65]) {
  constexpr int R = 4 * JT;
  if (!X) return;
  for (int k0 = 0; k0 < K; k0 += 64) {
    for (int e = tid; e < BB * 64; e += 256) {
      int r = e >> 6, c = e & 63;
      Xt[r][c] = (k0 + c < K) ? X[(long)r * xld + k0 + c] : 0.0f;
    }
    for (int e = tid; e < R * 64; e += 256) {
      int r = e >> 6, c = e & 63;
      int wr = (r / JT) * H + j0 + (r % JT);
      Wt[r][c] = (k0 + c < K) ? W[(long)wr * wld + k0 + c] : 0.0f;
    }
    __syncthreads();
#pragma unroll 8
    for (int kk = 0; kk < 64; ++kk) {
      float wv = Wt[tx][kk];
#pragma unroll
      for (int mm = 0; mm < MPT; ++mm)
        acc[mm] += Xt[ty * MPT + mm][kk] * wv;
    }
    __syncthreads();
  }
}

template<int JT>
__global__ __launch_bounds__(256) void cell_kernel(CellJobs2 jobs) {
  constexpr int R = 4 * JT;
  constexpr int GP = 256 / R;
  constexpr int MPT = 32 / GP;
  __shared__ float Wt[R][65];
  __shared__ float Xt[BB][65];
  const CellJob J = jobs.j[blockIdx.y];
  const int tid = threadIdx.x;
  const int tx = tid % R;
  const int ty = tid / R;
  const int j0 = blockIdx.x * JT;
  const int H = J.H;
  float acc[MPT];
#pragma unroll
  for (int i = 0; i < MPT; ++i) acc[i] = 0.0f;
  cell_accum<JT, MPT>(J.x0, J.x0ld, J.w0, J.w0ld, J.K0, H, j0, tid, tx, ty, acc, Wt, Xt);
  cell_accum<JT, MPT>(J.x1, J.x1ld, J.w1, J.w1ld, J.K1, H, j0, tid, tx, ty, acc, Wt, Xt);
  cell_accum<JT, MPT>(J.h, J.hld, J.whh, J.whhld, H, H, j0, tid, tx, ty, acc, Wt, Xt);
  const int wrow = (tx / JT) * H + j0 + (tx % JT);
  float bb = J.bhh[wrow] + (J.xp ? 0.0f : J.bih[wrow]);
  float* gb = &Wt[0][0];
#pragma unroll
  for (int mm = 0; mm < MPT; ++mm) {
    int m = ty * MPT + mm;
    float g = acc[mm] + bb;
    if (J.xp) g += J.xp[(long)m * J.xpld + wrow];
    gb[tx * 33 + m] = g;
  }
  __syncthreads();
  for (int e = tid; e < BB * JT; e += 256) {
    int j = e >> 5, m = e & 31;
    float iv = sigf(gb[(0 * JT + j) * 33 + m]);
    float fv = sigf(gb[(1 * JT + j) * 33 + m]);
    float gv = tanhf(gb[(2 * JT + j) * 33 + m]);
    float ov = sigf(gb[(3 * JT + j) * 33 + m]);
    float cold = J.cin ? J.cin[(long)m * J.cld + j0 + j] : 0.0f;
    float cnew = fv * cold + iv * gv;
    float hnew = ov * tanhf(cnew);
    J.cout[(long)m * J.coutld + j0 + j] = cnew;
    J.hout[(long)m * J.houtld + j0 + j] = hnew;
  }
}

__global__ void proj_kernel(const float* __restrict__ h, const float* __restrict__ w4,
                            const float* __restrict__ b4, float* __restrict__ pbuf,
                            float* __restrict__ outp) {
  int n = blockIdx.x, lane = threadIdx.x;
  float wr[16];
#pragma unroll
  for (int i = 0; i < 16; ++i) wr[i] = w4[n * NHD + lane + 64 * i];
  for (int b = 0; b < BB; ++b) {
    float s = 0.0f;
#pragma unroll
    for (int i = 0; i < 16; ++i) s += wr[i] * h[b * NHD + lane + 64 * i];
#pragma unroll
    for (int off = 32; off > 0; off >>= 1) s += __shfl_down(s, off);
    if (lane == 0) {
      float v = s + b4[n];
      pbuf[b * INPW + n] = v;
      outp[(long)b * (TT * INPW) + n] = v;
    }
  }
}

// =====================================================================
extern "C" void kernel_launch(void* const* d_in, const int* in_sizes, int n_in,
                              void* d_out, int out_size, void* d_ws, size_t ws_size,
                              hipStream_t stream) {
  (void)in_sizes; (void)n_in; (void)out_size;
  const float* x        = (const float*)d_in[0];
  const float* eps      = (const float*)d_in[1];
  const float* e0f_wih  = (const float*)d_in[2];
  const float* e0f_whh  = (const float*)d_in[3];
  const float* e0f_bih  = (const float*)d_in[4];
  const float* e0f_bhh  = (const float*)d_in[5];
  const float* e0b_wih  = (const float*)d_in[6];
  const float* e0b_whh  = (const float*)d_in[7];
  const float* e0b_bih  = (const float*)d_in[8];
  const float* e0b_bhh  = (const float*)d_in[9];
  const float* e1f_wih  = (const float*)d_in[10];
  const float* e1f_whh  = (const float*)d_in[11];
  const float* e1f_bih  = (const float*)d_in[12];
  const float* e1f_bhh  = (const float*)d_in[13];
  const float* e1b_wih  = (const float*)d_in[14];
  const float* e1b_whh  = (const float*)d_in[15];
  const float* e1b_bih  = (const float*)d_in[16];
  const float* e1b_bhh  = (const float*)d_in[17];
  const float* wm  = (const float*)d_in[18];
  const float* bm  = (const float*)d_in[19];
  const float* wsw = (const float*)d_in[20];
  const float* bsv = (const float*)d_in[21];
  const float* w2  = (const float*)d_in[22];
  const float* b2  = (const float*)d_in[23];
  const float* c0_wih = (const float*)d_in[24];
  const float* c0_whh = (const float*)d_in[25];
  const float* c0_bih = (const float*)d_in[26];
  const float* c0_bhh = (const float*)d_in[27];
  const float* c1_wih = (const float*)d_in[28];
  const float* c1_whh = (const float*)d_in[29];
  const float* c1_bih = (const float*)d_in[30];
  const float* c1_bhh = (const float*)d_in[31];
  const float* w3 = (const float*)d_in[32];
  const float* b3 = (const float*)d_in[33];
  const float* d1_wih = (const float*)d_in[34];
  const float* d1_whh = (const float*)d_in[35];
  const float* d1_bih = (const float*)d_in[36];
  const float* d1_bhh = (const float*)d_in[37];
  const float* d2_wih = (const float*)d_in[38];
  const float* d2_whh = (const float*)d_in[39];
  const float* d2_bih = (const float*)d_in[40];
  const float* d2_bhh = (const float*)d_in[41];
  const float* w4 = (const float*)d_in[42];
  const float* b4 = (const float*)d_in[43];
  (void)c0_wih;

  float* out = (float*)d_out;
  float* zm_out = out + (size_t)BB * TT * INPW;
  float* zs_out = zm_out + BB * NZ;

  // ---------- try new bf16 path allocation ----------
  char* wbase = (char*)d_ws;
  size_t cur = 0;
  auto AL = [&](size_t bytes) -> void* {
    void* p = wbase + cur;
    cur = (cur + bytes + 255) & ~(size_t)255;
    return p;
  };
  u16* xb    = (u16*)AL(2048L * 128 * 2);
  u16* e0wf  = (u16*)AL(8192L * 128 * 2);
  u16* e0wb  = (u16*)AL(8192L * 128 * 2);
  u16* e0hf  = (u16*)AL(8192L * 2048 * 2);
  u16* e0hb  = (u16*)AL(8192L * 2048 * 2);
  u16* e1wf  = (u16*)AL(8192L * 4096 * 2);
  u16* e1wb  = (u16*)AL(8192L * 4096 * 2);
  u16* e1hf  = (u16*)AL(8192L * 2048 * 2);
  u16* e1hb  = (u16*)AL(8192L * 2048 * 2);
  u16* c0h   = (u16*)AL(4096L * 1024 * 2);
  u16* c1w   = (u16*)AL(4096L * 1024 * 2);
  u16* c1h   = (u16*)AL(4096L * 1024 * 2);
  u16* d1we  = (u16*)AL(4096L * 1024 * 2);
  u16* d1wp  = (u16*)AL(4096L * 128 * 2);
  u16* d1h   = (u16*)AL(4096L * 1024 * 2);
  u16* d2w   = (u16*)AL(4096L * 1024 * 2);
  u16* d2h   = (u16*)AL(4096L * 1024 * 2);
  u16* w4b   = (u16*)AL(90L * 1024 * 2);
  u16* xp0f  = (u16*)AL(2048L * 8192 * 2);
  u16* xp0b  = (u16*)AL(2048L * 8192 * 2);
  u16* y0b   = (u16*)AL(2048L * 4096 * 2);
  u16* xp1f  = (u16*)AL(2048L * 8192 * 2);
  u16* xp1b  = (u16*)AL(2048L * 8192 * 2);
  u16* hb1f  = (u16*)AL(2L * 32 * 2048 * 2);
  u16* hb1b  = (u16*)AL(2L * 32 * 2048 * 2);
  u16* tvecb = (u16*)AL(32L * 4096 * 2);
  u16* yc0b  = (u16*)AL(4L * 32 * 1024 * 2);
  u16* embb  = (u16*)AL(4L * 32 * 1024 * 2);
  u16* sallb = (u16*)AL(128L * 4096 * 2);
  u16* xeb   = (u16*)AL(128L * 4096 * 2);
  u16* dh1b  = (u16*)AL(2L * 32 * 1024 * 2);
  u16* dh2b  = (u16*)AL(2L * 32 * 1024 * 2);
  u16* pbufb = (u16*)AL(32L * 128 * 2);
  float* c0f_ = (float*)AL(32L * 2048 * 4);
  float* c0b_ = (float*)AL(32L * 2048 * 4);
  float* c1f_ = (float*)AL(32L * 2048 * 4);
  float* c1b_ = (float*)AL(32L * 2048 * 4);
  float* htb  = (float*)AL(32L * 4096 * 4);
  float* zbuf = (float*)AL(32L * 512 * 4);
  float* tvec = (float*)AL(32L * 4096 * 4);
  float* cc0  = (float*)AL(32L * 1024 * 4);
  float* cc1  = (float*)AL(32L * 1024 * 4);
  float* embf = (float*)AL(128L * 1024 * 4);
  float* sall = (float*)AL(128L * 4096 * 4);
  float* dc1  = (float*)AL(32L * 1024 * 4);
  float* dc2  = (float*)AL(32L * 1024 * 4);
  bool newpath = (cur <= ws_size);

  if (newpath) {
    // ---- conversions ----
    auto cf = [&](const float* s, u16* d, long n) {
      cvt_flat<<<dim3((unsigned)((n / 4 + 255) / 256)), 256, 0, stream>>>(s, d, n);
    };
    cf(e0f_whh, e0hf, 8192L * 2048);
    cf(e0b_whh, e0hb, 8192L * 2048);
    cf(e1f_wih, e1wf, 8192L * 4096);
    cf(e1b_wih, e1wb, 8192L * 4096);
    cf(e1f_whh, e1hf, 8192L * 2048);
    cf(e1b_whh, e1hb, 8192L * 2048);
    cf(c0_whh, c0h, 4096L * 1024);
    cf(c1_wih, c1w, 4096L * 1024);
    cf(c1_whh, c1h, 4096L * 1024);
    cf(d1_whh, d1h, 4096L * 1024);
    cf(d2_wih, d2w, 4096L * 1024);
    cf(d2_whh, d2h, 4096L * 1024);
    cf(w4, w4b, 90L * 1024);
    cvt_pad<<<dim3(1, 8192), 128, 0, stream>>>(e0f_wih, 90, 90, e0wf, 128, 8192);
    cvt_pad<<<dim3(1, 8192), 128, 0, stream>>>(e0b_wih, 90, 90, e0wb, 128, 8192);
    cvt_pad<<<dim3(4, 4096), 256, 0, stream>>>(d1_wih, 1114, 1024, d1we, 1024, 4096);
    cvt_pad<<<dim3(1, 4096), 128, 0, stream>>>(d1_wih + 1024, 1114, 90, d1wp, 128, 4096);
    xcvt<<<dim3(2048), 128, 0, stream>>>(x, xb);

    // ---- layer-0 input projections ----
    gemm_bf<<<dim3(16, 64), 256, 0, stream>>>(xb, 128, e0wf, 128, e0f_bih, xp0f, 8192, 128);
    gemm_bf<<<dim3(16, 64), 256, 0, stream>>>(xb, 128, e0wb, 128, e0b_bih, xp0b, 8192, 128);

    // ---- encoder layer 0 ----
    for (int s = 0; s < TT; ++s) {
      int tf = s, tb = TT - 1 - s;
      BJobs2 js{};
      BJob& F = js.j[0];
      F.xh = s ? y0b + (long)(tf - 1) * 32 * 4096 : nullptr; F.xhld = 4096;
      F.wh = e0hf; F.whld = 2048; F.Kh = 2048;
      F.xp = xp0f + (long)tf * 32 * 8192; F.xpld = 8192;
      F.bih = e0f_bih; F.bhh = e0f_bhh; F.add_bih = 0;
      F.cin = s ? c0f_ : nullptr; F.cld = 2048;
      F.cout = c0f_; F.coutld = 2048;
      F.houtb = y0b + (long)tf * 32 * 4096; F.hbld = 4096;
      F.houtf = nullptr; F.hfld = 0; F.H = 2048;
      BJob& Bj = js.j[1];
      Bj = F;
      Bj.xh = s ? y0b + (long)(tb + 1) * 32 * 4096 + 2048 : nullptr;
      Bj.wh = e0hb; Bj.xp = xp0b + (long)tb * 32 * 8192;
      Bj.bih = e0b_bih; Bj.bhh = e0b_bhh;
      Bj.cin = s ? c0b_ : nullptr; Bj.cout = c0b_;
      Bj.houtb = y0b + (long)tb * 32 * 4096 + 2048;
      bcell<<<dim3(128, 2), 256, 0, stream>>>(js);
    }

    // ---- layer-1 input projections (big GEMMs) ----
    gemm_bf<<<dim3(16, 64), 256, 0, stream>>>(y0b, 4096, e1wf, 4096, e1f_bih, xp1f, 8192, 4096);
    gemm_bf<<<dim3(16, 64), 256, 0, stream>>>(y0b, 4096, e1wb, 4096, e1b_bih, xp1b, 8192, 4096);

    // ---- encoder layer 1 ----
    for (int s = 0; s < TT; ++s) {
      int tf = s, tb = TT - 1 - s;
      BJobs2 js{};
      BJob& F = js.j[0];
      F.xh = s ? hb1f + (long)((s - 1) & 1) * 32 * 2048 : nullptr; F.xhld = 2048;
      F.wh = e1hf; F.whld = 2048; F.Kh = 2048;
      F.xp = xp1f + (long)tf * 32 * 8192; F.xpld = 8192;
      F.bih = e1f_bih; F.bhh = e1f_bhh; F.add_bih = 0;
      F.cin = s ? c1f_ : nullptr; F.cld = 2048;
      F.cout = c1f_; F.coutld = 2048;
      F.houtb = hb1f + (long)(s & 1) * 32 * 2048; F.hbld = 2048;
      F.houtf = (s == TT - 1) ? htb : nullptr; F.hfld = 4096; F.H = 2048;
      BJob& Bj = js.j[1];
      Bj = F;
      Bj.xh = s ? hb1b + (long)((s - 1) & 1) * 32 * 2048 : nullptr;
      Bj.wh = e1hb; Bj.xp = xp1b + (long)tb * 32 * 8192;
      Bj.bih = e1b_bih; Bj.bhh = e1b_bhh;
      Bj.cin = s ? c1b_ : nullptr; Bj.cout = c1b_;
      Bj.houtb = hb1b + (long)(s & 1) * 32 * 2048;
      Bj.houtf = (s == TT - 1) ? htb + 2048 : nullptr;
      bcell<<<dim3(128, 2), 256, 0, stream>>>(js);
    }

    // ---- latent ----
    gemm128<<<dim3(1, 4), 256, 0, stream>>>(htb, 4096, wm, 4096, bm, zm_out, 512, 32, 4096, 0, nullptr);
    gemm128<<<dim3(1, 4), 256, 0, stream>>>(htb, 4096, wsw, 4096, bsv, zs_out, 512, 32, 4096, 2, nullptr);
    zcalc_kernel<<<dim3((BB * NZ + 255) / 256), 256, 0, stream>>>(zm_out, zs_out, eps, zbuf);
    gemm128<<<dim3(1, 32), 256, 0, stream>>>(zbuf, 512, w2, 512, b2, tvec, 4096, 32, 512, 1, tvecb);

    // ---- conductor ----
    for (int u = 0; u < NU; ++u) {
      {
        BJobs2 js{};
        BJob& J = js.j[0];
        J.xh = u ? yc0b + (long)(u - 1) * 32 * 1024 : tvecb; J.xhld = u ? 1024 : 4096;
        J.wh = c0h; J.whld = 1024; J.Kh = 1024;
        J.bih = c0_bih; J.bhh = c0_bhh; J.add_bih = 1;
        J.cin = u ? cc0 : tvec + 2048; J.cld = u ? 1024 : 4096;
        J.cout = cc0; J.coutld = 1024;
        J.houtb = yc0b + (long)u * 32 * 1024; J.hbld = 1024;
        J.houtf = nullptr; J.hfld = 0; J.H = 1024;
        js.j[1] = J;
        bcell<<<dim3(64, 1), 256, 0, stream>>>(js);
      }
      {
        BJobs2 js{};
        BJob& J = js.j[0];
        J.xa = yc0b + (long)u * 32 * 1024; J.xald = 1024; J.wa = c1w; J.wald = 1024; J.Ka = 1024;
        J.xh = u ? embb + (long)(u - 1) * 32 * 1024 : tvecb + 1024; J.xhld = u ? 1024 : 4096;
        J.wh = c1h; J.whld = 1024; J.Kh = 1024;
        J.bih = c1_bih; J.bhh = c1_bhh; J.add_bih = 1;
        J.cin = u ? cc1 : tvec + 3072; J.cld = u ? 1024 : 4096;
        J.cout = cc1; J.coutld = 1024;
        J.houtb = embb + (long)u * 32 * 1024; J.hbld = 1024;
        J.houtf = embf + (long)u * 32 * 1024; J.hfld = 1024; J.H = 1024;
        js.j[1] = J;
        bcell<<<dim3(64, 1), 256, 0, stream>>>(js);
      }
    }

    // ---- decoder prep ----
    gemm128<<<dim3(1, 32), 256, 0, stream>>>(embf, 1024, w3, 1024, b3, sall, 4096, 128, 1024, 1, sallb);
    gemm_bf<<<dim3(1, 32), 256, 0, stream>>>(embb, 1024, d1we, 1024, d1_bih, xeb, 4096, 1024);
    zero_us<<<dim3(16), 256, 0, stream>>>(pbufb, 32 * 128);

    // ---- hierarchical decoder ----
    for (int t = 0; t < TT; ++t) {
      int u = t >> 4, sg = t & 15;
      {
        BJobs2 js{};
        BJob& J = js.j[0];
        J.xa = pbufb; J.xald = 128; J.wa = d1wp; J.wald = 128; J.Ka = 128;
        J.xh = sg ? dh1b + (long)((sg - 1) & 1) * 32 * 1024 : sallb + (long)u * 32 * 4096;
        J.xhld = sg ? 1024 : 4096;
        J.wh = d1h; J.whld = 1024; J.Kh = 1024;
        J.xp = xeb + (long)u * 32 * 4096; J.xpld = 4096;
        J.bih = d1_bih; J.bhh = d1_bhh; J.add_bih = 0;
        J.cin = sg ? dc1 : sall + (long)u * 32 * 4096 + 2048; J.cld = sg ? 1024 : 4096;
        J.cout = dc1; J.coutld = 1024;
        J.houtb = dh1b + (long)(sg & 1) * 32 * 1024; J.hbld = 1024;
        J.houtf = nullptr; J.hfld = 0; J.H = 1024;
        js.j[1] = J;
        bcell<<<dim3(64, 1), 256, 0, stream>>>(js);
      }
      {
        BJobs2 js{};
        BJob& J = js.j[0];
        J.xa = dh1b + (long)(sg & 1) * 32 * 1024; J.xald = 1024; J.wa = d2w; J.wald = 1024; J.Ka = 1024;
        J.xh = sg ? dh2b + (long)((sg - 1) & 1) * 32 * 1024 : sallb + (long)u * 32 * 4096 + 1024;
        J.xhld = sg ? 1024 : 4096;
        J.wh = d2h; J.whld = 1024; J.Kh = 1024;
        J.bih = d2_bih; J.bhh = d2_bhh; J.add_bih = 1;
        J.cin = sg ? dc2 : sall + (long)u * 32 * 4096 + 3072; J.cld = sg ? 1024 : 4096;
        J.cout = dc2; J.coutld = 1024;
        J.houtb = dh2b + (long)(sg & 1) * 32 * 1024; J.hbld = 1024;
        J.houtf = nullptr; J.hfld = 0; J.H = 1024;
        js.j[1] = J;
        bcell<<<dim3(64, 1), 256, 0, stream>>>(js);
      }
      projb<<<dim3(INPW), 64, 0, stream>>>(
          dh2b + (long)(sg & 1) * 32 * 1024, w4b, b4, pbufb, out + (size_t)t * INPW);
    }
    softmax_kernel<<<dim3(BB * TT), 64, 0, stream>>>(out);
    return;
  }

  // ================= old fp32 fallback path =================
  float* wsp = (float*)d_ws;
  size_t off = 0;
  auto alloc = [&](size_t n) { float* p = wsp + off; off += (n + 63) & ~(size_t)63; return p; };
  float* y0  = alloc((size_t)BB * TT * 2 * NH1);
  float* c0f = alloc(BB * NH1); float* c0b = alloc(BB * NH1);
  float* c1f = alloc(BB * NH1); float* c1b = alloc(BB * NH1);
  float* hpf = alloc(2 * BB * NH1); float* hpb = alloc(2 * BB * NH1);
  float* htbo = alloc(BB * 2 * NH1);
  float* zbufo = alloc(BB * NZ);
  float* tveco = alloc(BB * 4 * NHC);
  float* yc0 = alloc(BB * NU * NHC);
  float* emb = alloc(BB * NU * NHC);
  float* cc0o = alloc(BB * NHC); float* cc1o = alloc(BB * NHC);
  float* sallo = alloc((size_t)BB * NU * 4 * NHD);
  float* dh1 = alloc(2 * BB * NHD); float* dh2 = alloc(2 * BB * NHD);
  float* dc1o = alloc(BB * NHD); float* dc2o = alloc(BB * NHD);
  float* pbuf = alloc(BB * INPW);
  size_t need_xp = off + 2 * ((size_t)BB * TT * 4 * NH1 + 64);
  bool use_xp = ws_size >= need_xp * sizeof(float);
  float* xp1f_ = nullptr; float* xp1b_ = nullptr;
  if (use_xp) { xp1f_ = alloc((size_t)BB * TT * 4 * NH1); xp1b_ = alloc((size_t)BB * TT * 4 * NH1); }

  for (int s = 0; s < TT; ++s) {
    CellJobs2 js{};
    int tf = s, tb = TT - 1 - s;
    CellJob& F = js.j[0];
    F.x0 = x + tf * INPW; F.x0ld = TT * INPW; F.w0 = e0f_wih; F.w0ld = INPW; F.K0 = INPW;
    F.h = s ? y0 + (size_t)(tf - 1) * 2 * NH1 : nullptr; F.hld = TT * 2 * NH1;
    F.whh = e0f_whh; F.whhld = NH1;
    F.bih = e0f_bih; F.bhh = e0f_bhh;
    F.cin = s ? c0f : nullptr; F.cld = NH1;
    F.cout = c0f; F.coutld = NH1;
    F.hout = y0 + (size_t)tf * 2 * NH1; F.houtld = TT * 2 * NH1;
    F.H = NH1;
    CellJob& Bj = js.j[1];
    Bj = F;
    Bj.x0 = x + tb * INPW; Bj.w0 = e0b_wih;
    Bj.h = s ? y0 + (size_t)(tb + 1) * 2 * NH1 + NH1 : nullptr;
    Bj.whh = e0b_whh; Bj.bih = e0b_bih; Bj.bhh = e0b_bhh;
    Bj.cin = s ? c0b : nullptr; Bj.cout = c0b;
    Bj.hout = y0 + (size_t)tb * 2 * NH1 + NH1;
    cell_kernel<16><<<dim3(NH1 / 16, 2), 256, 0, stream>>>(js);
  }
  if (use_xp) {
    gemm128<<<dim3(16, 64), 256, 0, stream>>>(y0, 2 * NH1, e1f_wih, 2 * NH1, e1f_bih,
                                              xp1f_, 4 * NH1, BB * TT, 2 * NH1, 0, nullptr);
    gemm128<<<dim3(16, 64), 256, 0, stream>>>(y0, 2 * NH1, e1b_wih, 2 * NH1, e1b_bih,
                                              xp1b_, 4 * NH1, BB * TT, 2 * NH1, 0, nullptr);
  }
  for (int s = 0; s < TT; ++s) {
    CellJobs2 js{};
    int tf = s, tb = TT - 1 - s;
    CellJob& F = js.j[0];
    if (use_xp) { F.xp = xp1f_ + (size_t)tf * 4 * NH1; F.xpld = TT * 4 * NH1; }
    else { F.x0 = y0 + (size_t)tf * 2 * NH1; F.x0ld = TT * 2 * NH1; F.w0 = e1f_wih; F.w0ld = 2 * NH1; F.K0 = 2 * NH1; }
    F.h = s ? hpf + (size_t)((s - 1) & 1) * BB * NH1 : nullptr; F.hld = NH1;
    F.whh = e1f_whh; F.whhld = NH1;
    F.bih = e1f_bih; F.bhh = e1f_bhh;
    F.cin = s ? c1f : nullptr; F.cld = NH1;
    F.cout = c1f; F.coutld = NH1;
    F.hout = hpf + (size_t)(s & 1) * BB * NH1; F.houtld = NH1;
    F.H = NH1;
    CellJob& Bj = js.j[1];
    Bj = F;
    if (use_xp) { Bj.xp = xp1b_ + (size_t)tb * 4 * NH1; }
    else { Bj.x0 = y0 + (size_t)tb * 2 * NH1; Bj.w0 = e1b_wih; }
    Bj.h = s ? hpb + (size_t)((s - 1) & 1) * BB * NH1 : nullptr;
    Bj.whh = e1b_whh; Bj.bih = e1b_bih; Bj.bhh = e1b_bhh;
    Bj.cin = s ? c1b : nullptr; Bj.cout = c1b;
    Bj.hout = hpb + (size_t)(s & 1) * BB * NH1;
    cell_kernel<16><<<dim3(NH1 / 16, 2), 256, 0, stream>>>(js);
  }
  concat_ht_kernel<<<dim3((BB * 2 * NH1 + 255) / 256), 256, 0, stream>>>(
      hpf + BB * NH1, hpb + BB * NH1, htbo);
  gemm128<<<dim3(1, NZ / 128), 256, 0, stream>>>(htbo, 2 * NH1, wm, 2 * NH1, bm,
                                                 zm_out, NZ, BB, 2 * NH1, 0, nullptr);
  gemm128<<<dim3(1, NZ / 128), 256, 0, stream>>>(htbo, 2 * NH1, wsw, 2 * NH1, bsv,
                                                 zs_out, NZ, BB, 2 * NH1, 2, nullptr);
  zcalc_kernel<<<dim3((BB * NZ + 255) / 256), 256, 0, stream>>>(zm_out, zs_out, eps, zbufo);
  gemm128<<<dim3(1, 4 * NHC / 128), 256, 0, stream>>>(zbufo, NZ, w2, NZ, b2,
                                                      tveco, 4 * NHC, BB, NZ, 1, nullptr);
  for (int u = 0; u < NU; ++u) {
    {
      CellJobs2 js{};
      CellJob& J = js.j[0];
      J.h = u ? yc0 + (size_t)(u - 1) * NHC : tveco; J.hld = u ? NU * NHC : 4 * NHC;
      J.whh = c0_whh; J.whhld = NHC;
      J.bih = c0_bih; J.bhh = c0_bhh;
      J.cin = u ? cc0o : tveco + 2 * NHC; J.cld = u ? NHC : 4 * NHC;
      J.cout = cc0o; J.coutld = NHC;
      J.hout = yc0 + (size_t)u * NHC; J.houtld = NU * NHC;
      J.H = NHC;
      js.j[1] = J;
      cell_kernel<8><<<dim3(NHC / 8, 1), 256, 0, stream>>>(js);
    }
    {
      CellJobs2 js{};
      CellJob& J = js.j[0];
      J.x0 = yc0 + (size_t)u * NHC; J.x0ld = NU * NHC; J.w0 = c1_wih; J.w0ld = NHC; J.K0 = NHC;
      J.h = u ? emb + (size_t)(u - 1) * NHC : tveco + NHC; J.hld = u ? NU * NHC : 4 * NHC;
      J.whh = c1_whh; J.whhld = NHC;
      J.bih = c1_bih; J.bhh = c1_bhh;
      J.cin = u ? cc1o : tveco + 3 * NHC; J.cld = u ? NHC : 4 * NHC;
      J.cout = cc1o; J.coutld = NHC;
      J.hout = emb + (size_t)u * NHC; J.houtld = NU * NHC;
      J.H = NHC;
      js.j[1] = J;
      cell_kernel<8><<<dim3(NHC / 8, 1), 256, 0, stream>>>(js);
    }
  }
  gemm128<<<dim3(1, 4 * NHD / 128), 256, 0, stream>>>(emb, NHC, w3, NHC, b3,
                                                      sallo, 4 * NHD, BB * NU, NHC, 1, nullptr);
  zero_kernel<<<dim3((BB * INPW + 255) / 256), 256, 0, stream>>>(pbuf, BB * INPW);
  for (int t = 0; t < TT; ++t) {
    int u = t >> 4, sg = t & 15;
    {
      CellJobs2 js{};
      CellJob& J = js.j[0];
      J.x0 = emb + (size_t)u * NHC; J.x0ld = NU * NHC; J.w0 = d1_wih; J.w0ld = NHC + INPW; J.K0 = NHC;
      J.x1 = pbuf; J.x1ld = INPW; J.w1 = d1_wih + NHC; J.w1ld = NHC + INPW; J.K1 = INPW;
      J.h = sg ? dh1 + (size_t)((sg - 1) & 1) * BB * NHD : sallo + (size_t)u * 4 * NHD;
      J.hld = sg ? NHD : NU * 4 * NHD;
      J.whh = d1_whh; J.whhld = NHD;
      J.bih = d1_bih; J.bhh = d1_bhh;
      J.cin = sg ? dc1o : sallo + (size_t)u * 4 * NHD + 2 * NHD; J.cld = sg ? NHD : NU * 4 * NHD;
      J.cout = dc1o; J.coutld = NHD;
      J.hout = dh1 + (size_t)(sg & 1) * BB * NHD; J.houtld = NHD;
      J.H = NHD;
      js.j[1] = J;
      cell_kernel<8><<<dim3(NHD / 8, 1), 256, 0, stream>>>(js);
    }
    {
      CellJobs2 js{};
      CellJob& J = js.j[0];
      J.x0 = dh1 + (size_t)(sg & 1) * BB * NHD; J.x0ld = NHD; J.w0 = d2_wih; J.w0ld = NHD; J.K0 = NHD;
      J.h = sg ? dh2 + (size_t)((sg - 1) & 1) * BB * NHD : sallo + (size_t)u * 4 * NHD + NHD;
      J.hld = sg ? NHD : NU * 4 * NHD;
      J.whh = d2_whh; J.whhld = NHD;
      J.bih = d2_bih; J.bhh = d2_bhh;
      J.cin = sg ? dc2o : sallo + (size_t)u * 4 * NHD + 3 * NHD; J.cld = sg ? NHD : NU * 4 * NHD;
      J.cout = dc2o; J.coutld = NHD;
      J.hout = dh2 + (size_t)(sg & 1) * BB * NHD; J.houtld = NHD;
      J.H = NHD;
      js.j[1] = J;
      cell_kernel<8><<<dim3(NHD / 8, 1), 256, 0, stream>>>(js);
    }
    proj_kernel<<<dim3(INPW), 64, 0, stream>>>(
        dh2 + (size_t)(sg & 1) * BB * NHD, w4, b4, pbuf, out + (size_t)t * INPW);
  }
  softmax_kernel<<<dim3(BB * TT), 64, 0, stream>>>(out);
}